// Round 1
// baseline (223.292 us; speedup 1.0000x reference)
//
#include <hip/hip_runtime.h>
#include <hip/hip_bf16.h>

typedef __attribute__((ext_vector_type(8))) short bf16x8;
typedef __attribute__((ext_vector_type(4))) float f32x4;

#define RPB 4  // rows per block in prep kernel

__device__ __forceinline__ float sigmoidf_(float v) {
    return 1.0f / (1.0f + __expf(-v));
}

// ---------------------------------------------------------------------------
// Kernel 0: cd_w2 [256,128] f32 -> w2t [128][256] bf16 (transposed for MFMA B)
// ---------------------------------------------------------------------------
__global__ __launch_bounds__(256) void convw2_kernel(
    const float* __restrict__ w2, __hip_bfloat16* __restrict__ w2t)
{
    int tid = blockIdx.x * 256 + threadIdx.x;   // 32768 total
    int n = tid >> 8, k = tid & 255;
    w2t[n * 256 + k] = __float2bfloat16(w2[k * 128 + n]);
}

// ---------------------------------------------------------------------------
// Kernel 1: per-object heads + U/V precompute.
// U = x @ cd_w1[:512] + cd_b1   (bias folded here)
// V = x @ cd_w1[512:]
// hidden = relu(x @ pp_w1 + pp_b1); only cols 0..3 of pp_w2 are needed.
// ---------------------------------------------------------------------------
__global__ __launch_bounds__(256) void prep_kernel(
    const float* __restrict__ x,
    const float* __restrict__ pp_w1, const float* __restrict__ pp_b1,
    const float* __restrict__ pp_w2, const float* __restrict__ pp_b2,
    const float* __restrict__ cd_w1, const float* __restrict__ cd_b1,
    const float* __restrict__ vel_w, const float* __restrict__ vel_b,
    const float* __restrict__ frc_w, const float* __restrict__ frc_b,
    float* __restrict__ out, float* __restrict__ Ug, float* __restrict__ Vg)
{
    __shared__ float xs[RPB][512];   // 8 KB
    __shared__ float hid[RPB][512];  // 8 KB
    const int t = threadIdx.x;
    const int row0 = blockIdx.x * RPB;  // global row in [0,1024)

    { // stage 4 contiguous x rows (4*512 floats)
        const float4* xg4 = (const float4*)(x + row0 * 512);
        float4* xs4 = (float4*)&xs[0][0];
        xs4[t]       = xg4[t];
        xs4[t + 256] = xg4[t + 256];
    }
    __syncthreads();

    { // hidden = relu(x @ pp_w1 + b1): thread t owns cols t and t+256
        const float* w1p = pp_w1 + t;
        float acc0[RPB] = {0.f,0.f,0.f,0.f}, acc1[RPB] = {0.f,0.f,0.f,0.f};
        #pragma unroll 4
        for (int k = 0; k < 512; ++k) {
            float w0 = w1p[0], w1v = w1p[256];
            w1p += 512;
            #pragma unroll
            for (int r = 0; r < RPB; ++r) {
                float xv = xs[r][k];            // LDS broadcast (uniform k)
                acc0[r] = fmaf(xv, w0, acc0[r]);
                acc1[r] = fmaf(xv, w1v, acc1[r]);
            }
        }
        float b0 = pp_b1[t], b1 = pp_b1[t + 256];
        #pragma unroll
        for (int r = 0; r < RPB; ++r) {
            hid[r][t]       = fmaxf(acc0[r] + b0, 0.0f);
            hid[r][t + 256] = fmaxf(acc1[r] + b1, 0.0f);
        }
    }

    { // U/V: thread t owns col t (256 cols)
        const float* wUp = cd_w1 + t;
        const float* wVp = cd_w1 + 512 * 256 + t;
        float accU[RPB] = {0.f,0.f,0.f,0.f}, accV[RPB] = {0.f,0.f,0.f,0.f};
        #pragma unroll 4
        for (int k = 0; k < 512; ++k) {
            float wU = wUp[0], wV = wVp[0];
            wUp += 256; wVp += 256;
            #pragma unroll
            for (int r = 0; r < RPB; ++r) {
                float xv = xs[r][k];
                accU[r] = fmaf(xv, wU, accU[r]);
                accV[r] = fmaf(xv, wV, accV[r]);
            }
        }
        float bU = cd_b1[t];
        #pragma unroll
        for (int r = 0; r < RPB; ++r) {
            Ug[(row0 + r) * 256 + t] = accU[r] + bU;
            Vg[(row0 + r) * 256 + t] = accV[r];
        }
    }
    __syncthreads();  // hid fully written before head dots

    if (t < 16) { // mass/friction/elasticity/density: (r, c) = (t>>2, t&3)
        int r = t >> 2, c = t & 3;
        const float* w2p = pp_w2 + c;
        float acc = 0.f;
        for (int k = 0; k < 512; ++k) acc = fmaf(hid[r][k], w2p[k * 128], acc);
        acc += pp_b2[c];
        float s = sigmoidf_(acc);
        float val = (c == 0) ? s * 100.f : (c == 3) ? s * 10.f : s;
        // out layout: mass @0, friction @1024, elasticity @2048, density @3072
        out[c * 1024 + row0 + r] = val;
    } else if (t >= 64 && t < 76) { // velocities: 4 rows x 3 cols
        int idx = t - 64; int r = idx / 3, c = idx % 3;
        const float* wp = vel_w + c;
        float acc = 0.f;
        for (int k = 0; k < 512; ++k) acc = fmaf(xs[r][k], wp[k * 3], acc);
        out[4096 + (row0 + r) * 3 + c] = acc + vel_b[c];
    } else if (t >= 128 && t < 140) { // forces
        int idx = t - 128; int r = idx / 3, c = idx % 3;
        const float* wp = frc_w + c;
        float acc = 0.f;
        for (int k = 0; k < 512; ++k) acc = fmaf(xs[r][k], wp[k * 3], acc);
        out[7168 + (row0 + r) * 3 + c] = acc + frc_b[c];
    }
}

// ---------------------------------------------------------------------------
// Kernel 2: pair MLP. 8x8 (i,j) tile per block, upper triangle only.
// h1 = relu(U_i + V_j)  -> bf16 in LDS [64][264]
// g  = h1 @ cd_w2 + b2  -> MFMA 16x16x32 bf16; 4 waves split 128 cols (2 nt each)
// prob = sigmoid(relu(g) @ cd_w3 + b3) -> symmetric scatter, 0 diagonal
// ---------------------------------------------------------------------------
__global__ __launch_bounds__(256) void pair_kernel(
    const float* __restrict__ Ug, const float* __restrict__ Vg,
    const __hip_bfloat16* __restrict__ w2t,  // [128][256] bf16
    const float* __restrict__ cd_b2, const float* __restrict__ cd_w3,
    const float* __restrict__ cd_b3, float* __restrict__ cm)
{
    const int tj = blockIdx.x, ti = blockIdx.y, b = blockIdx.z;
    if (ti > tj) return;

    __shared__ __align__(16) float Us[8][260];   // +4 pad: conflict-free f4 reads
    __shared__ __align__(16) float Vs[8][260];
    __shared__ __align__(16) short hs[64][264];  // bf16 h, +8 pad: 2-way b128 reads
    __shared__ float ps[64][4];                  // cross-wave layer-3 partials

    const int t = threadIdx.x;
    const int i0 = ti * 8, j0 = tj * 8;

    { // stage U rows (8 i's) and V rows (8 j's): 8 KB each, coalesced
        const float4* Ug4 = (const float4*)(Ug + (b * 256 + i0) * 256);
        const float4* Vg4 = (const float4*)(Vg + (b * 256 + j0) * 256);
        #pragma unroll
        for (int c = t; c < 512; c += 256) {
            int row = c >> 6, col = (c & 63) << 2;
            *(float4*)&Us[row][col] = Ug4[c];
            *(float4*)&Vs[row][col] = Vg4[c];
        }
    }
    __syncthreads();

    { // h[p][k] = relu(U[pi][k] + V[pj][k]) as bf16; wave w handles k-quarter w
        const int p  = t & 63;
        const int pi = p >> 3, pj = p & 7;
        const int kb = (t >> 6) * 64;
        #pragma unroll
        for (int kk = 0; kk < 64; kk += 8) {
            float4 u0 = *(const float4*)&Us[pi][kb + kk];
            float4 u1 = *(const float4*)&Us[pi][kb + kk + 4];
            float4 v0 = *(const float4*)&Vs[pj][kb + kk];
            float4 v1 = *(const float4*)&Vs[pj][kb + kk + 4];
            float hv[8] = {u0.x + v0.x, u0.y + v0.y, u0.z + v0.z, u0.w + v0.w,
                           u1.x + v1.x, u1.y + v1.y, u1.z + v1.z, u1.w + v1.w};
            bf16x8 pack;
            #pragma unroll
            for (int u = 0; u < 8; ++u) {
                union { __hip_bfloat16 h; short s; } cv;
                cv.h = __float2bfloat16(fmaxf(hv[u], 0.0f));
                pack[u] = cv.s;
            }
            *(bf16x8*)&hs[p][kb + kk] = pack;
        }
    }
    __syncthreads();

    const int wave = t >> 6, lane = t & 63;
    const int l = lane & 15, q = lane >> 4;

    f32x4 acc[4][2] = {};  // [mt][nt2], 32 VGPRs
    #pragma unroll
    for (int ks = 0; ks < 8; ++ks) {
        // B fragments: wave's 2 column-tiles; b_frag[j] = w2[k=ks*32+q*8+j][n]
        bf16x8 bfr0 = *(const bf16x8*)(w2t + ((wave * 2 + 0) * 16 + l) * 256 + ks * 32 + q * 8);
        bf16x8 bfr1 = *(const bf16x8*)(w2t + ((wave * 2 + 1) * 16 + l) * 256 + ks * 32 + q * 8);
        #pragma unroll
        for (int mt = 0; mt < 4; ++mt) {
            // A fragment: a[j] = h[pair=mt*16+l][k=ks*32+q*8+j]
            bf16x8 afr = *(const bf16x8*)&hs[mt * 16 + l][ks * 32 + q * 8];
            acc[mt][0] = __builtin_amdgcn_mfma_f32_16x16x32_bf16(afr, bfr0, acc[mt][0], 0, 0, 0);
            acc[mt][1] = __builtin_amdgcn_mfma_f32_16x16x32_bf16(afr, bfr1, acc[mt][1], 0, 0, 0);
        }
    }

    // epilogue: +b2, relu, dot w3 over this wave's 32 cols, quad-shuffle reduce
    float b2v0 = cd_b2[(wave * 2 + 0) * 16 + l], b2v1 = cd_b2[(wave * 2 + 1) * 16 + l];
    float w3v0 = cd_w3[(wave * 2 + 0) * 16 + l], w3v1 = cd_w3[(wave * 2 + 1) * 16 + l];
    #pragma unroll
    for (int mt = 0; mt < 4; ++mt) {
        #pragma unroll
        for (int r = 0; r < 4; ++r) {
            // D layout: pair = mt*16 + q*4 + r, col = nt*16 + l
            float g0 = fmaxf(acc[mt][0][r] + b2v0, 0.f);
            float g1 = fmaxf(acc[mt][1][r] + b2v1, 0.f);
            float s = g0 * w3v0 + g1 * w3v1;
            s += __shfl_xor(s, 1);
            s += __shfl_xor(s, 2);
            s += __shfl_xor(s, 4);
            s += __shfl_xor(s, 8);
            if (l == 0) ps[mt * 16 + q * 4 + r][wave] = s;
        }
    }
    __syncthreads();

    if (t < 64) {
        int p = t;
        float v = ps[p][0] + ps[p][1] + ps[p][2] + ps[p][3] + cd_b3[0];
        float prob = 1.0f / (1.0f + __expf(-v));
        int i = i0 + (p >> 3), j = j0 + (p & 7);
        float* base = cm + b * 65536;
        if (i < j) {
            base[i * 256 + j] = prob;
            base[j * 256 + i] = prob;
        } else if (i == j) {
            base[i * 256 + i] = 0.0f;
        }
    }
}

// ---------------------------------------------------------------------------
extern "C" void kernel_launch(void* const* d_in, const int* in_sizes, int n_in,
                              void* d_out, int out_size, void* d_ws, size_t ws_size,
                              hipStream_t stream) {
    const float* x     = (const float*)d_in[0];
    const float* pp_w1 = (const float*)d_in[1];
    const float* pp_b1 = (const float*)d_in[2];
    const float* pp_w2 = (const float*)d_in[3];
    const float* pp_b2 = (const float*)d_in[4];
    const float* cd_w1 = (const float*)d_in[5];
    const float* cd_b1 = (const float*)d_in[6];
    const float* cd_w2 = (const float*)d_in[7];
    const float* cd_b2 = (const float*)d_in[8];
    const float* cd_w3 = (const float*)d_in[9];
    const float* cd_b3 = (const float*)d_in[10];
    const float* vel_w = (const float*)d_in[11];
    const float* vel_b = (const float*)d_in[12];
    const float* frc_w = (const float*)d_in[13];
    const float* frc_b = (const float*)d_in[14];

    float* out = (float*)d_out;
    // workspace: U [1024,256] f32 (1 MB) | V [1024,256] f32 (1 MB) | w2t bf16 (64 KB)
    float* Ug = (float*)d_ws;
    float* Vg = Ug + 1024 * 256;
    __hip_bfloat16* w2t = (__hip_bfloat16*)(Vg + 1024 * 256);

    convw2_kernel<<<dim3(128), dim3(256), 0, stream>>>(cd_w2, w2t);
    prep_kernel<<<dim3(256), dim3(256), 0, stream>>>(
        x, pp_w1, pp_b1, pp_w2, pp_b2, cd_w1, cd_b1,
        vel_w, vel_b, frc_w, frc_b, out, Ug, Vg);
    pair_kernel<<<dim3(32, 32, 4), dim3(256), 0, stream>>>(
        Ug, Vg, w2t, cd_b2, cd_w3, cd_b3, out + 10240);
}

// Round 2
// 186.972 us; speedup vs baseline: 1.1943x; 1.1943x over previous
//
#include <hip/hip_runtime.h>
#include <hip/hip_bf16.h>

typedef __attribute__((ext_vector_type(8))) short bf16x8;
typedef __attribute__((ext_vector_type(4))) float f32x4;

__device__ __forceinline__ float sigmoidf_(float v) {
    return 1.0f / (1.0f + __expf(-v));
}

__device__ __forceinline__ short f2bf(float f) {
    union { __hip_bfloat16 h; short s; } cv;
    cv.h = __float2bfloat16(f);
    return cv.s;
}

// ---------------------------------------------------------------------------
// Kernel 0: conversions.
//  xb [1024][512] bf16  = bf16(x)                         (ids 0 .. 524287)
//  Wt [1024][512] bf16, n-major:                          (ids 524288 .. 1048575)
//     n<512   : pp_w1[k*512 + n]
//     512-767 : cd_w1[k*256 + (n-512)]        (U half)
//     768-1023: cd_w1[(512+k)*256 + (n-768)]  (V half)
//  w2t [128][256] bf16 = cd_w2^T                          (ids 1048576 .. 1081343)
// ---------------------------------------------------------------------------
__global__ __launch_bounds__(256) void convert_kernel(
    const float* __restrict__ x, const float* __restrict__ pp_w1,
    const float* __restrict__ cd_w1, const float* __restrict__ cd_w2,
    __hip_bfloat16* __restrict__ xb, __hip_bfloat16* __restrict__ Wt,
    __hip_bfloat16* __restrict__ w2t)
{
    int id = blockIdx.x * 256 + threadIdx.x;
    if (id < 524288) {
        xb[id] = __float2bfloat16(x[id]);
    } else if (id < 1048576) {
        int j = id - 524288;
        int n = j >> 9, k = j & 511;
        float v;
        if (n < 512)      v = pp_w1[k * 512 + n];
        else if (n < 768) v = cd_w1[k * 256 + (n - 512)];
        else              v = cd_w1[(512 + k) * 256 + (n - 768)];
        Wt[j] = __float2bfloat16(v);
    } else {
        int j = id - 1048576;
        int n = j >> 8, k = j & 255;
        w2t[n * 256 + k] = __float2bfloat16(cd_w2[k * 128 + n]);
    }
}

// ---------------------------------------------------------------------------
// Kernel 1: fused MFMA GEMM  C[1024][1024] = xb @ Wt^T (Wt is n-major).
// One wave per 16-row x 32-col tile; fragments straight from global (L2).
// Epilogue by column region: hid (bf16, relu+b1) | U (+cd_b1) | V.
// ---------------------------------------------------------------------------
__global__ __launch_bounds__(256) void gemm_kernel(
    const __hip_bfloat16* __restrict__ xb, const __hip_bfloat16* __restrict__ Wt,
    const float* __restrict__ pp_b1, const float* __restrict__ cd_b1,
    __hip_bfloat16* __restrict__ hidg, float* __restrict__ Ug,
    float* __restrict__ Vg)
{
    const int t = threadIdx.x;
    const int wave = t >> 6, lane = t & 63;
    const int l = lane & 15, q = lane >> 4;
    const int m0 = blockIdx.y * 16;                 // 64 row tiles
    const int n0 = blockIdx.x * 128 + wave * 32;    // 8 col blocks x 4 waves

    const __hip_bfloat16* ap  = xb + (m0 + l) * 512 + q * 8;
    const __hip_bfloat16* b0p = Wt + (n0 + l) * 512 + q * 8;
    const __hip_bfloat16* b1p = Wt + (n0 + 16 + l) * 512 + q * 8;

    f32x4 acc0 = {}, acc1 = {};
    #pragma unroll
    for (int ks = 0; ks < 16; ++ks) {
        bf16x8 a  = *(const bf16x8*)(ap  + ks * 32);
        bf16x8 b0 = *(const bf16x8*)(b0p + ks * 32);
        bf16x8 b1 = *(const bf16x8*)(b1p + ks * 32);
        acc0 = __builtin_amdgcn_mfma_f32_16x16x32_bf16(a, b0, acc0, 0, 0, 0);
        acc1 = __builtin_amdgcn_mfma_f32_16x16x32_bf16(a, b1, acc1, 0, 0, 0);
    }

    // C/D layout: col = l, row = q*4 + r
    const int c0 = n0 + l, c1 = n0 + 16 + l;
    if (n0 < 512) {
        float b0v = pp_b1[c0], b1v = pp_b1[c1];
        #pragma unroll
        for (int r = 0; r < 4; ++r) {
            int rg = m0 + q * 4 + r;
            hidg[rg * 512 + c0] = __float2bfloat16(fmaxf(acc0[r] + b0v, 0.f));
            hidg[rg * 512 + c1] = __float2bfloat16(fmaxf(acc1[r] + b1v, 0.f));
        }
    } else if (n0 < 768) {
        float b0v = cd_b1[c0 - 512], b1v = cd_b1[c1 - 512];
        #pragma unroll
        for (int r = 0; r < 4; ++r) {
            int rg = m0 + q * 4 + r;
            Ug[rg * 256 + (c0 - 512)] = acc0[r] + b0v;
            Ug[rg * 256 + (c1 - 512)] = acc1[r] + b1v;
        }
    } else {
        #pragma unroll
        for (int r = 0; r < 4; ++r) {
            int rg = m0 + q * 4 + r;
            Vg[rg * 256 + (c0 - 768)] = acc0[r];
            Vg[rg * 256 + (c1 - 768)] = acc1[r];
        }
    }
}

// ---------------------------------------------------------------------------
// Kernel 2: heads. Block = 16 rows; p[:,0:4] from hidg, vel/frc from x.
// ---------------------------------------------------------------------------
__global__ __launch_bounds__(256) void heads_kernel(
    const float* __restrict__ x, const __hip_bfloat16* __restrict__ hidg,
    const float* __restrict__ pp_w2, const float* __restrict__ pp_b2,
    const float* __restrict__ vel_w, const float* __restrict__ vel_b,
    const float* __restrict__ frc_w, const float* __restrict__ frc_b,
    float* __restrict__ out)
{
    __shared__ float xs[16 * 512];            // 32 KB
    __shared__ __hip_bfloat16 hsm[16 * 512];  // 16 KB
    const int t = threadIdx.x;
    const int r0 = blockIdx.x * 16;

    {
        const float4* xg = (const float4*)(x + r0 * 512);
        float4* xs4 = (float4*)xs;
        #pragma unroll
        for (int i = 0; i < 8; ++i) xs4[t + i * 256] = xg[t + i * 256];
        const uint4* hg = (const uint4*)(hidg + r0 * 512);
        uint4* hs4 = (uint4*)hsm;
        #pragma unroll
        for (int i = 0; i < 4; ++i) hs4[t + i * 256] = hg[t + i * 256];
    }
    __syncthreads();

    if (t >= 160) return;
    const int row = t & 15, head = t >> 4;
    const int rg = r0 + row;

    if (head < 4) {
        const int c = head;
        const float* wp = pp_w2 + c;
        float acc = 0.f;
        #pragma unroll 8
        for (int k = 0; k < 512; ++k)
            acc = fmaf(__bfloat162float(hsm[row * 512 + k]), wp[k * 128], acc);
        acc += pp_b2[c];
        float s = sigmoidf_(acc);
        float val = (c == 0) ? s * 100.f : (c == 3) ? s * 10.f : s;
        out[c * 1024 + rg] = val;   // mass @0, friction @1024, elast @2048, dens @3072
    } else if (head < 7) {
        const int c = head - 4;
        const float* wp = vel_w + c;
        float acc = 0.f;
        #pragma unroll 8
        for (int k = 0; k < 512; ++k)
            acc = fmaf(xs[row * 512 + k], wp[k * 3], acc);
        out[4096 + rg * 3 + c] = acc + vel_b[c];
    } else {
        const int c = head - 7;
        const float* wp = frc_w + c;
        float acc = 0.f;
        #pragma unroll 8
        for (int k = 0; k < 512; ++k)
            acc = fmaf(xs[row * 512 + k], wp[k * 3], acc);
        out[7168 + rg * 3 + c] = acc + frc_b[c];
    }
}

// ---------------------------------------------------------------------------
// Kernel 3: pair MLP (unchanged from round 1). 8x8 (i,j) tile per block.
// ---------------------------------------------------------------------------
__global__ __launch_bounds__(256) void pair_kernel(
    const float* __restrict__ Ug, const float* __restrict__ Vg,
    const __hip_bfloat16* __restrict__ w2t,  // [128][256] bf16
    const float* __restrict__ cd_b2, const float* __restrict__ cd_w3,
    const float* __restrict__ cd_b3, float* __restrict__ cm)
{
    const int tj = blockIdx.x, ti = blockIdx.y, b = blockIdx.z;
    if (ti > tj) return;

    __shared__ __align__(16) float Us[8][260];
    __shared__ __align__(16) float Vs[8][260];
    __shared__ __align__(16) short hs[64][264];
    __shared__ float ps[64][4];

    const int t = threadIdx.x;
    const int i0 = ti * 8, j0 = tj * 8;

    {
        const float4* Ug4 = (const float4*)(Ug + (b * 256 + i0) * 256);
        const float4* Vg4 = (const float4*)(Vg + (b * 256 + j0) * 256);
        #pragma unroll
        for (int c = t; c < 512; c += 256) {
            int row = c >> 6, col = (c & 63) << 2;
            *(float4*)&Us[row][col] = Ug4[c];
            *(float4*)&Vs[row][col] = Vg4[c];
        }
    }
    __syncthreads();

    {
        const int p  = t & 63;
        const int pi = p >> 3, pj = p & 7;
        const int kb = (t >> 6) * 64;
        #pragma unroll
        for (int kk = 0; kk < 64; kk += 8) {
            float4 u0 = *(const float4*)&Us[pi][kb + kk];
            float4 u1 = *(const float4*)&Us[pi][kb + kk + 4];
            float4 v0 = *(const float4*)&Vs[pj][kb + kk];
            float4 v1 = *(const float4*)&Vs[pj][kb + kk + 4];
            float hv[8] = {u0.x + v0.x, u0.y + v0.y, u0.z + v0.z, u0.w + v0.w,
                           u1.x + v1.x, u1.y + v1.y, u1.z + v1.z, u1.w + v1.w};
            bf16x8 pack;
            #pragma unroll
            for (int u = 0; u < 8; ++u) pack[u] = f2bf(fmaxf(hv[u], 0.0f));
            *(bf16x8*)&hs[p][kb + kk] = pack;
        }
    }
    __syncthreads();

    const int wave = t >> 6, lane = t & 63;
    const int l = lane & 15, q = lane >> 4;

    f32x4 acc[4][2] = {};
    #pragma unroll
    for (int ks = 0; ks < 8; ++ks) {
        bf16x8 bfr0 = *(const bf16x8*)(w2t + ((wave * 2 + 0) * 16 + l) * 256 + ks * 32 + q * 8);
        bf16x8 bfr1 = *(const bf16x8*)(w2t + ((wave * 2 + 1) * 16 + l) * 256 + ks * 32 + q * 8);
        #pragma unroll
        for (int mt = 0; mt < 4; ++mt) {
            bf16x8 afr = *(const bf16x8*)&hs[mt * 16 + l][ks * 32 + q * 8];
            acc[mt][0] = __builtin_amdgcn_mfma_f32_16x16x32_bf16(afr, bfr0, acc[mt][0], 0, 0, 0);
            acc[mt][1] = __builtin_amdgcn_mfma_f32_16x16x32_bf16(afr, bfr1, acc[mt][1], 0, 0, 0);
        }
    }

    float b2v0 = cd_b2[(wave * 2 + 0) * 16 + l], b2v1 = cd_b2[(wave * 2 + 1) * 16 + l];
    float w3v0 = cd_w3[(wave * 2 + 0) * 16 + l], w3v1 = cd_w3[(wave * 2 + 1) * 16 + l];
    #pragma unroll
    for (int mt = 0; mt < 4; ++mt) {
        #pragma unroll
        for (int r = 0; r < 4; ++r) {
            float g0 = fmaxf(acc[mt][0][r] + b2v0, 0.f);
            float g1 = fmaxf(acc[mt][1][r] + b2v1, 0.f);
            float s = g0 * w3v0 + g1 * w3v1;
            s += __shfl_xor(s, 1);
            s += __shfl_xor(s, 2);
            s += __shfl_xor(s, 4);
            s += __shfl_xor(s, 8);
            if (l == 0) ps[mt * 16 + q * 4 + r][wave] = s;
        }
    }
    __syncthreads();

    if (t < 64) {
        int p = t;
        float v = ps[p][0] + ps[p][1] + ps[p][2] + ps[p][3] + cd_b3[0];
        float prob = 1.0f / (1.0f + __expf(-v));
        int i = i0 + (p >> 3), j = j0 + (p & 7);
        float* base = cm + b * 65536;
        if (i < j) {
            base[i * 256 + j] = prob;
            base[j * 256 + i] = prob;
        } else if (i == j) {
            base[i * 256 + i] = 0.0f;
        }
    }
}

// ---------------------------------------------------------------------------
extern "C" void kernel_launch(void* const* d_in, const int* in_sizes, int n_in,
                              void* d_out, int out_size, void* d_ws, size_t ws_size,
                              hipStream_t stream) {
    const float* x     = (const float*)d_in[0];
    const float* pp_w1 = (const float*)d_in[1];
    const float* pp_b1 = (const float*)d_in[2];
    const float* pp_w2 = (const float*)d_in[3];
    const float* pp_b2 = (const float*)d_in[4];
    const float* cd_w1 = (const float*)d_in[5];
    const float* cd_b1 = (const float*)d_in[6];
    const float* cd_w2 = (const float*)d_in[7];
    const float* cd_b2 = (const float*)d_in[8];
    const float* cd_w3 = (const float*)d_in[9];
    const float* cd_b3 = (const float*)d_in[10];
    const float* vel_w = (const float*)d_in[11];
    const float* vel_b = (const float*)d_in[12];
    const float* frc_w = (const float*)d_in[13];
    const float* frc_b = (const float*)d_in[14];

    float* out = (float*)d_out;
    // ws layout: Ug f32 1MB | Vg f32 1MB | xb bf16 1MB | Wt bf16 1MB |
    //            hidg bf16 1MB | w2t bf16 64KB   (total ~5.1 MB)
    float* Ug = (float*)d_ws;
    float* Vg = Ug + 262144;
    __hip_bfloat16* xb   = (__hip_bfloat16*)(Vg + 262144);
    __hip_bfloat16* Wt   = xb + 524288;
    __hip_bfloat16* hidg = Wt + 524288;
    __hip_bfloat16* w2t  = hidg + 524288;

    convert_kernel<<<dim3(4224), dim3(256), 0, stream>>>(
        x, pp_w1, cd_w1, cd_w2, xb, Wt, w2t);
    gemm_kernel<<<dim3(8, 64), dim3(256), 0, stream>>>(
        xb, Wt, pp_b1, cd_b1, hidg, Ug, Vg);
    heads_kernel<<<dim3(64), dim3(256), 0, stream>>>(
        x, hidg, pp_w2, pp_b2, vel_w, vel_b, frc_w, frc_b, out);
    pair_kernel<<<dim3(32, 32, 4), dim3(256), 0, stream>>>(
        Ug, Vg, w2t, cd_b2, cd_w3, cd_b3, out + 10240);
}

// Round 3
// 134.243 us; speedup vs baseline: 1.6633x; 1.3928x over previous
//
#include <hip/hip_runtime.h>
#include <hip/hip_bf16.h>

typedef __attribute__((ext_vector_type(8))) short bf16x8;
typedef __attribute__((ext_vector_type(4))) float f32x4;

__device__ __forceinline__ float sigmoidf_(float v) {
    return 1.0f / (1.0f + __expf(-v));
}
__device__ __forceinline__ short f2bf(float f) {
    union { __hip_bfloat16 h; short s; } cv;
    cv.h = __float2bfloat16(f);
    return cv.s;
}
__device__ __forceinline__ float bf2f(short s) {
    union { float f; unsigned u; } cv;
    cv.u = ((unsigned)(unsigned short)s) << 16;
    return cv.f;
}

// ---------------------------------------------------------------------------
// Kernel 0: conversions, all coalesced.
//  b in [0,256)  : xb[1024][512] = bf16(x), 8 elems/thread
//  b in [256,320): transpose pp_w1 [512k][512n] -> Wt rows 0..511
//  b in [320,384): transpose cd_w1 [1024k][256n] -> Wt rows 512..1023 (U|V)
//  b in [384,392): transpose cd_w2 [256k][128n] -> w2t [128][256]
//  b == 392      : pack hw[10][512]: pp_w2 cols 0-3, vel_w cols, frc_w cols
// ---------------------------------------------------------------------------
__global__ __launch_bounds__(256) void convert_kernel(
    const float* __restrict__ x, const float* __restrict__ pp_w1,
    const float* __restrict__ cd_w1, const float* __restrict__ cd_w2,
    const float* __restrict__ pp_w2, const float* __restrict__ vel_w,
    const float* __restrict__ frc_w,
    __hip_bfloat16* __restrict__ xb, __hip_bfloat16* __restrict__ Wt,
    __hip_bfloat16* __restrict__ w2t, float* __restrict__ hw)
{
    __shared__ float ts[64][65];
    const int b = blockIdx.x, t = threadIdx.x;

    if (b < 256) {  // xb cast
        int base = b * 2048 + t * 8;
        float4 a = *(const float4*)(x + base);
        float4 c = *(const float4*)(x + base + 4);
        bf16x8 o;
        o[0] = f2bf(a.x); o[1] = f2bf(a.y); o[2] = f2bf(a.z); o[3] = f2bf(a.w);
        o[4] = f2bf(c.x); o[5] = f2bf(c.y); o[6] = f2bf(c.z); o[7] = f2bf(c.w);
        *(bf16x8*)(xb + base) = o;
        return;
    }
    if (b == 392) {  // hw pack (tiny, strided reads but only 5120 elems)
        for (int e = t; e < 5120; e += 256) {
            int h = e >> 9, k = e & 511;
            float v = (h < 4) ? pp_w2[k * 128 + h]
                    : (h < 7) ? vel_w[k * 3 + (h - 4)]
                              : frc_w[k * 3 + (h - 7)];
            hw[e] = v;
        }
        return;
    }

    // --- 64x64 tile transpose regions ---
    const float* src; int ss, k0, n0, region;
    if (b < 320)      { int i = b - 256; src = pp_w1; ss = 512; k0 = (i >> 3) * 64; n0 = (i & 7) * 64; region = 0; }
    else if (b < 384) { int i = b - 320; src = cd_w1; ss = 256; k0 = (i >> 2) * 64; n0 = (i & 3) * 64; region = 1; }
    else              { int i = b - 384; src = cd_w2; ss = 128; k0 = (i >> 1) * 64; n0 = (i & 1) * 64; region = 2; }

    #pragma unroll
    for (int i = 0; i < 4; ++i) {   // read coalesced
        int r = (t >> 4) + i * 16, c4 = (t & 15) * 4;
        *(float4*)&ts[r][c4] = *(const float4*)(src + (k0 + r) * ss + n0 + c4);
    }
    __syncthreads();
    #pragma unroll
    for (int i = 0; i < 4; ++i) {   // write transposed, coalesced in k
        int nOut = (t >> 4) + i * 16, kc = (t & 15) * 4;
        ushort4 o;
        o.x = (unsigned short)f2bf(ts[kc + 0][nOut]);
        o.y = (unsigned short)f2bf(ts[kc + 1][nOut]);
        o.z = (unsigned short)f2bf(ts[kc + 2][nOut]);
        o.w = (unsigned short)f2bf(ts[kc + 3][nOut]);
        int gn = n0 + nOut, gk = k0 + kc;
        if (region == 0)      *(ushort4*)(Wt + gn * 512 + gk) = o;
        else if (region == 1) {
            int row = (gk < 512) ? (512 + gn) : (768 + gn);
            *(ushort4*)(Wt + row * 512 + (gk & 511)) = o;
        } else                *(ushort4*)(w2t + gn * 256 + gk) = o;
    }
}

// ---------------------------------------------------------------------------
// Kernel 1: fused MFMA GEMM C[1024][1024] = xb @ Wt^T. 2x2 tile per wave
// (32 rows x 32 cols), fragments straight from L2. grid (8 n-blocks, 32 m).
// ---------------------------------------------------------------------------
__global__ __launch_bounds__(256) void gemm_kernel(
    const __hip_bfloat16* __restrict__ xb, const __hip_bfloat16* __restrict__ Wt,
    const float* __restrict__ pp_b1, const float* __restrict__ cd_b1,
    __hip_bfloat16* __restrict__ hidg, float* __restrict__ Ug,
    float* __restrict__ Vg)
{
    const int t = threadIdx.x;
    const int wave = t >> 6, lane = t & 63;
    const int l = lane & 15, q = lane >> 4;
    const int m0 = blockIdx.y * 32;
    const int n0 = blockIdx.x * 128 + wave * 32;

    const __hip_bfloat16* a0p = xb + (m0 + l) * 512 + q * 8;
    const __hip_bfloat16* a1p = a0p + 16 * 512;
    const __hip_bfloat16* b0p = Wt + (n0 + l) * 512 + q * 8;
    const __hip_bfloat16* b1p = b0p + 16 * 512;

    f32x4 acc00 = {}, acc01 = {}, acc10 = {}, acc11 = {};
    #pragma unroll
    for (int ks = 0; ks < 16; ++ks) {
        bf16x8 a0 = *(const bf16x8*)(a0p + ks * 32);
        bf16x8 a1 = *(const bf16x8*)(a1p + ks * 32);
        bf16x8 b0 = *(const bf16x8*)(b0p + ks * 32);
        bf16x8 b1 = *(const bf16x8*)(b1p + ks * 32);
        acc00 = __builtin_amdgcn_mfma_f32_16x16x32_bf16(a0, b0, acc00, 0, 0, 0);
        acc01 = __builtin_amdgcn_mfma_f32_16x16x32_bf16(a0, b1, acc01, 0, 0, 0);
        acc10 = __builtin_amdgcn_mfma_f32_16x16x32_bf16(a1, b0, acc10, 0, 0, 0);
        acc11 = __builtin_amdgcn_mfma_f32_16x16x32_bf16(a1, b1, acc11, 0, 0, 0);
    }

    // C/D layout: col = l, row = q*4 + r
    const int c0 = n0 + l, c1 = n0 + 16 + l;
    #pragma unroll
    for (int mt = 0; mt < 2; ++mt) {
        const f32x4& A0 = mt ? acc10 : acc00;
        const f32x4& A1 = mt ? acc11 : acc01;
        if (n0 < 512) {
            float b0v = pp_b1[c0], b1v = pp_b1[c1];
            #pragma unroll
            for (int r = 0; r < 4; ++r) {
                int rg = m0 + mt * 16 + q * 4 + r;
                hidg[rg * 512 + c0] = __float2bfloat16(fmaxf(A0[r] + b0v, 0.f));
                hidg[rg * 512 + c1] = __float2bfloat16(fmaxf(A1[r] + b1v, 0.f));
            }
        } else if (n0 < 768) {
            float b0v = cd_b1[c0 - 512], b1v = cd_b1[c1 - 512];
            #pragma unroll
            for (int r = 0; r < 4; ++r) {
                int rg = m0 + mt * 16 + q * 4 + r;
                Ug[rg * 256 + (c0 - 512)] = A0[r] + b0v;
                Ug[rg * 256 + (c1 - 512)] = A1[r] + b1v;
            }
        } else {
            #pragma unroll
            for (int r = 0; r < 4; ++r) {
                int rg = m0 + mt * 16 + q * 4 + r;
                Vg[rg * 256 + (c0 - 768)] = A0[r];
                Vg[rg * 256 + (c1 - 768)] = A1[r];
            }
        }
    }
}

// ---------------------------------------------------------------------------
// Kernel 2: heads. One wave per row; 10 coalesced shuffle-reduce dots.
// ---------------------------------------------------------------------------
__global__ __launch_bounds__(256) void heads_kernel(
    const float* __restrict__ x, const __hip_bfloat16* __restrict__ hidg,
    const float* __restrict__ hw, const float* __restrict__ pp_b2,
    const float* __restrict__ vel_b, const float* __restrict__ frc_b,
    float* __restrict__ out)
{
    const int t = threadIdx.x, wave = t >> 6, lane = t & 63;
    const int row = blockIdx.x * 4 + wave;   // 0..1023

    const float4* xr = (const float4*)(x + row * 512);
    float4 xa = xr[lane * 2], xc = xr[lane * 2 + 1];
    bf16x8 hb = *(const bf16x8*)(hidg + row * 512 + lane * 8);
    float hf[8];
    #pragma unroll
    for (int j = 0; j < 8; ++j) hf[j] = bf2f(hb[j]);

    #pragma unroll
    for (int h = 0; h < 10; ++h) {
        const float4* wr = (const float4*)(hw + h * 512);
        float4 wa = wr[lane * 2], wc = wr[lane * 2 + 1];
        float s;
        if (h < 4) {
            s = hf[0]*wa.x + hf[1]*wa.y + hf[2]*wa.z + hf[3]*wa.w
              + hf[4]*wc.x + hf[5]*wc.y + hf[6]*wc.z + hf[7]*wc.w;
        } else {
            s = xa.x*wa.x + xa.y*wa.y + xa.z*wa.z + xa.w*wa.w
              + xc.x*wc.x + xc.y*wc.y + xc.z*wc.z + xc.w*wc.w;
        }
        s += __shfl_xor(s, 1);  s += __shfl_xor(s, 2);
        s += __shfl_xor(s, 4);  s += __shfl_xor(s, 8);
        s += __shfl_xor(s, 16); s += __shfl_xor(s, 32);
        if (lane == 0) {
            if (h < 4) {
                float sg = sigmoidf_(s + pp_b2[h]);
                out[h * 1024 + row] = (h == 0) ? sg * 100.f : (h == 3) ? sg * 10.f : sg;
            } else if (h < 7) {
                out[4096 + row * 3 + (h - 4)] = s + vel_b[h - 4];
            } else {
                out[7168 + row * 3 + (h - 7)] = s + frc_b[h - 7];
            }
        }
    }
}

// ---------------------------------------------------------------------------
// Kernel 3: pair MLP. Triangular 1D grid (528 tiles x 4 batches); A-fragments
// built directly in registers from Us/Vs (no hs LDS, one barrier less).
// ---------------------------------------------------------------------------
__global__ __launch_bounds__(256) void pair_kernel(
    const float* __restrict__ Ug, const float* __restrict__ Vg,
    const __hip_bfloat16* __restrict__ w2t,  // [128][256] bf16
    const float* __restrict__ cd_b2, const float* __restrict__ cd_w3,
    const float* __restrict__ cd_b3, float* __restrict__ cm)
{
    const int b = blockIdx.y;
    const int tp = blockIdx.x;  // 0..527, (ti<=tj) of 32x32 tiles
    // decode triangular: S(t) = t*(65-t)/2
    int ti = (int)((65.0f - sqrtf(4225.0f - 8.0f * (float)tp)) * 0.5f);
    while ((ti + 1) * (65 - (ti + 1)) / 2 <= tp) ++ti;
    while (ti * (65 - ti) / 2 > tp) --ti;
    const int tj = ti + (tp - ti * (65 - ti) / 2);

    __shared__ __align__(16) float Us[8][264];
    __shared__ __align__(16) float Vs[8][264];
    __shared__ float ps[64][4];

    const int t = threadIdx.x;
    const int i0 = ti * 8, j0 = tj * 8;

    {
        const float4* Ug4 = (const float4*)(Ug + (b * 256 + i0) * 256);
        const float4* Vg4 = (const float4*)(Vg + (b * 256 + j0) * 256);
        #pragma unroll
        for (int c = t; c < 512; c += 256) {
            int row = c >> 6, col = (c & 63) << 2;
            *(float4*)&Us[row][col] = Ug4[c];
            *(float4*)&Vs[row][col] = Vg4[c];
        }
    }
    __syncthreads();

    const int wave = t >> 6, lane = t & 63;
    const int l = lane & 15, q = lane >> 4;
    const int pj = l & 7, piB = l >> 3;

    const __hip_bfloat16* wb0 = w2t + ((wave * 2 + 0) * 16 + l) * 256 + q * 8;
    const __hip_bfloat16* wb1 = wb0 + 16 * 256;

    f32x4 acc[4][2] = {};
    #pragma unroll
    for (int ks = 0; ks < 8; ++ks) {
        bf16x8 bfr0 = *(const bf16x8*)(wb0 + ks * 32);
        bf16x8 bfr1 = *(const bf16x8*)(wb1 + ks * 32);
        const int kk = ks * 32 + q * 8;
        #pragma unroll
        for (int mt = 0; mt < 4; ++mt) {
            const int pi = mt * 2 + piB;
            float4 u0 = *(const float4*)&Us[pi][kk];
            float4 u1 = *(const float4*)&Us[pi][kk + 4];
            float4 v0 = *(const float4*)&Vs[pj][kk];
            float4 v1 = *(const float4*)&Vs[pj][kk + 4];
            bf16x8 afr;
            afr[0] = f2bf(fmaxf(u0.x + v0.x, 0.f));
            afr[1] = f2bf(fmaxf(u0.y + v0.y, 0.f));
            afr[2] = f2bf(fmaxf(u0.z + v0.z, 0.f));
            afr[3] = f2bf(fmaxf(u0.w + v0.w, 0.f));
            afr[4] = f2bf(fmaxf(u1.x + v1.x, 0.f));
            afr[5] = f2bf(fmaxf(u1.y + v1.y, 0.f));
            afr[6] = f2bf(fmaxf(u1.z + v1.z, 0.f));
            afr[7] = f2bf(fmaxf(u1.w + v1.w, 0.f));
            acc[mt][0] = __builtin_amdgcn_mfma_f32_16x16x32_bf16(afr, bfr0, acc[mt][0], 0, 0, 0);
            acc[mt][1] = __builtin_amdgcn_mfma_f32_16x16x32_bf16(afr, bfr1, acc[mt][1], 0, 0, 0);
        }
    }

    // epilogue: +b2, relu, dot w3 over wave's 32 cols, 16-lane shuffle reduce
    float b2v0 = cd_b2[(wave * 2 + 0) * 16 + l], b2v1 = cd_b2[(wave * 2 + 1) * 16 + l];
    float w3v0 = cd_w3[(wave * 2 + 0) * 16 + l], w3v1 = cd_w3[(wave * 2 + 1) * 16 + l];
    #pragma unroll
    for (int mt = 0; mt < 4; ++mt) {
        #pragma unroll
        for (int r = 0; r < 4; ++r) {
            // D layout: pair = mt*16 + q*4 + r, col = nt*16 + l
            float g0 = fmaxf(acc[mt][0][r] + b2v0, 0.f);
            float g1 = fmaxf(acc[mt][1][r] + b2v1, 0.f);
            float s = g0 * w3v0 + g1 * w3v1;
            s += __shfl_xor(s, 1);
            s += __shfl_xor(s, 2);
            s += __shfl_xor(s, 4);
            s += __shfl_xor(s, 8);
            if (l == 0) ps[mt * 16 + q * 4 + r][wave] = s;
        }
    }
    __syncthreads();

    if (t < 64) {
        int p = t;
        float v = ps[p][0] + ps[p][1] + ps[p][2] + ps[p][3] + cd_b3[0];
        float prob = 1.0f / (1.0f + __expf(-v));
        int i = i0 + (p >> 3), j = j0 + (p & 7);
        float* base = cm + b * 65536;
        if (i < j) {
            base[i * 256 + j] = prob;
            base[j * 256 + i] = prob;
        } else if (i == j) {
            base[i * 256 + i] = 0.0f;
        }
    }
}

// ---------------------------------------------------------------------------
extern "C" void kernel_launch(void* const* d_in, const int* in_sizes, int n_in,
                              void* d_out, int out_size, void* d_ws, size_t ws_size,
                              hipStream_t stream) {
    const float* x     = (const float*)d_in[0];
    const float* pp_w1 = (const float*)d_in[1];
    const float* pp_b1 = (const float*)d_in[2];
    const float* pp_w2 = (const float*)d_in[3];
    const float* pp_b2 = (const float*)d_in[4];
    const float* cd_w1 = (const float*)d_in[5];
    const float* cd_b1 = (const float*)d_in[6];
    const float* cd_w2 = (const float*)d_in[7];
    const float* cd_b2 = (const float*)d_in[8];
    const float* cd_w3 = (const float*)d_in[9];
    const float* cd_b3 = (const float*)d_in[10];
    const float* vel_w = (const float*)d_in[11];
    const float* vel_b = (const float*)d_in[12];
    const float* frc_w = (const float*)d_in[13];
    const float* frc_b = (const float*)d_in[14];

    float* out = (float*)d_out;
    // ws: Ug 1MB | Vg 1MB | xb 1MB | Wt 1MB | hidg 1MB | w2t 64KB | hw 20KB
    float* Ug = (float*)d_ws;
    float* Vg = Ug + 262144;
    __hip_bfloat16* xb   = (__hip_bfloat16*)(Vg + 262144);
    __hip_bfloat16* Wt   = xb + 524288;
    __hip_bfloat16* hidg = Wt + 524288;
    __hip_bfloat16* w2t  = hidg + 524288;
    float* hw = (float*)(w2t + 32768);

    convert_kernel<<<dim3(393), dim3(256), 0, stream>>>(
        x, pp_w1, cd_w1, cd_w2, pp_w2, vel_w, frc_w, xb, Wt, w2t, hw);
    gemm_kernel<<<dim3(8, 32), dim3(256), 0, stream>>>(
        xb, Wt, pp_b1, cd_b1, hidg, Ug, Vg);
    heads_kernel<<<dim3(256), dim3(256), 0, stream>>>(
        x, hidg, hw, pp_b2, vel_b, frc_b, out);
    pair_kernel<<<dim3(528, 4), dim3(256), 0, stream>>>(
        Ug, Vg, w2t, cd_b2, cd_w3, cd_b3, out + 10240);
}